// Round 6
// baseline (227.635 us; speedup 1.0000x reference)
//
#include <hip/hip_runtime.h>

#define EPS 1e-5f
// B=64, D=2048, E=64, H1=512, H2=256

typedef __attribute__((ext_vector_type(8))) short short8;
typedef __attribute__((ext_vector_type(4))) float f32x4;

__device__ __forceinline__ unsigned short f2bf(float f) {
  unsigned u = __float_as_uint(f);
  u = u + 0x7FFFu + ((u >> 16) & 1u);  // RNE
  return (unsigned short)(u >> 16);
}
__device__ __forceinline__ unsigned pack2(float a, float b) {
  return (unsigned)f2bf(a) | ((unsigned)f2bf(b) << 16);
}

// ================= merged prep (385 blocks x 256 thr) =================
// x<256    : Qf/Rf (fp32, frag layout [cs:16][k:2048][32]) for 8 k each
// 256..319 : W2f (bf16, frag layout [cs:16][o:256][32])
// x==320   : t2, c2
// 321..384 : Pf rows for b = x-321 (fp32 frag layout [cs:16][b:64][32])
__global__ __launch_bounds__(256) void prep_all(
    const float* __restrict__ rep,
    const float* __restrict__ emb, const float* __restrict__ W1,
    const float* __restrict__ g1, const float* __restrict__ v1,
    const float* __restrict__ b1, const float* __restrict__ m1,
    const float* __restrict__ beta1,
    const float* __restrict__ W2,
    const float* __restrict__ g2, const float* __restrict__ v2,
    const float* __restrict__ b2, const float* __restrict__ m2,
    const float* __restrict__ beta2,
    float* __restrict__ Qf, float* __restrict__ Rf,
    unsigned short* __restrict__ W2f,
    float* __restrict__ t2, float* __restrict__ c2,
    float* __restrict__ Pf) {
  __shared__ float red[4 * 512];
  const int x = blockIdx.x, t = threadIdx.x;
  if (x < 256) {
    const int k0 = x * 8;
    const int h = t * 2;
    const float a0 = g1[h] * rsqrtf(v1[h] + EPS);
    const float a1 = g1[h + 1] * rsqrtf(v1[h + 1] + EPS);
    const float* We = W1 + 2048 * 512;
    float acc0[8], acc1[8];
    #pragma unroll
    for (int k = 0; k < 8; ++k) { acc0[k] = 0.f; acc1[k] = 0.f; }
    for (int e = 0; e < 64; ++e) {
      float2 wv = *(const float2*)(We + e * 512 + h);
      #pragma unroll
      for (int k = 0; k < 8; ++k) {
        float ev = emb[(k0 + k) * 64 + e];  // block-uniform
        acc0[k] = fmaf(ev, wv.x, acc0[k]);
        acc1[k] = fmaf(ev, wv.y, acc1[k]);
      }
    }
    const int cs = h >> 5;
    const int rm = h & 31;
    #pragma unroll
    for (int k = 0; k < 8; ++k) {
      const int kk = k0 + k;
      *(float2*)(Qf + cs * 65536 + kk * 32 + rm) = make_float2(a0 * acc0[k], a1 * acc1[k]);
      float2 wv = *(const float2*)(W1 + (size_t)kk * 512 + h);
      *(float2*)(Rf + cs * 65536 + kk * 32 + rm) = make_float2(a0 * wv.x, a1 * wv.y);
    }
  } else if (x < 320) {
    const int h0 = (x - 256) * 8;
    const int o = t;
    unsigned d[4];
    #pragma unroll
    for (int i = 0; i < 4; ++i) {
      float v0 = W2[(h0 + 2 * i) * 256 + o];
      float v1_ = W2[(h0 + 2 * i + 1) * 256 + o];
      d[i] = pack2(v0, v1_);
    }
    const int cs = h0 >> 5;
    const int rm = h0 & 31;
    *(uint4*)(W2f + cs * 8192 + o * 32 + rm) = make_uint4(d[0], d[1], d[2], d[3]);
  } else if (x == 320) {
    float tv = g2[t] * rsqrtf(v2[t] + EPS);
    t2[t] = tv;
    c2[t] = tv * (b2[t] - m2[t]) + beta2[t];
  } else {
    // Pf for b = x - 321: 4 kq-slices of 512 k x 64 h-octet lanes
    const int b = x - 321;
    const int lane = t & 63, kq = t >> 6;
    const int h = lane * 8;
    const float* wp = W1 + (size_t)(kq * 512) * 512 + h;
    const float* rp = rep + b * 2048 + kq * 512;
    float acc[8];
    #pragma unroll
    for (int i = 0; i < 8; ++i) acc[i] = 0.f;
    #pragma unroll 4
    for (int k = 0; k < 512; ++k) {
      f32x4 wa = *(const f32x4*)(wp + (size_t)k * 512);
      f32x4 wb = *(const f32x4*)(wp + (size_t)k * 512 + 4);
      float rk = rp[k];  // wave-uniform
      acc[0] = fmaf(rk, wa[0], acc[0]); acc[1] = fmaf(rk, wa[1], acc[1]);
      acc[2] = fmaf(rk, wa[2], acc[2]); acc[3] = fmaf(rk, wa[3], acc[3]);
      acc[4] = fmaf(rk, wb[0], acc[4]); acc[5] = fmaf(rk, wb[1], acc[5]);
      acc[6] = fmaf(rk, wb[2], acc[6]); acc[7] = fmaf(rk, wb[3], acc[7]);
    }
    *(f32x4*)(&red[kq * 512 + h])     = (f32x4){acc[0], acc[1], acc[2], acc[3]};
    *(f32x4*)(&red[kq * 512 + h + 4]) = (f32x4){acc[4], acc[5], acc[6], acc[7]};
    __syncthreads();
    #pragma unroll
    for (int i = 0; i < 2; ++i) {
      const int hh = t + i * 256;
      float tot = red[hh] + red[512 + hh] + red[1024 + hh] + red[1536 + hh];
      float a = g1[hh] * rsqrtf(v1[hh] + EPS);
      float val = fmaf(a, tot, fmaf(a, b1[hh] - m1[hh], beta1[hh]));
      Pf[(hh >> 5) * 2048 + b * 32 + (hh & 31)] = val;
    }
  }
}

// ================= fused main =================
// 512 thr (8 waves: wm=w>>2 in {0,1}, wn=w&3), wave-tile 64x64, block M=128
// (2 k), N=256, K=512 in 16 chunks of 32. 1024 blocks.
// Single barrier per chunk; A gen'd to LDS (frag-order, 1x redundancy);
// B staged reg->LDS padded stride 40 (conflict-free reads); P dist-2 reg
// pipeline; Q/R in LDS once (broadcast reads). All global loads >=1 full
// iteration ahead of use, so the barrier vmcnt drain is free.
__global__ __launch_bounds__(512, 2) void fused_main(
    const float* __restrict__ rep,
    const float* __restrict__ Pf,
    const float* __restrict__ Qf,
    const float* __restrict__ Rf,
    const unsigned short* __restrict__ W2f,
    const float* __restrict__ t2, const float* __restrict__ c2,
    const float* __restrict__ W3, const float* __restrict__ b3,
    float* __restrict__ out) {
  __shared__ unsigned short Abuf[2][4096];       // 2 x 8KB, frag-ordered
  __shared__ unsigned short Bbuf[2][256 * 40];   // 2 x 20KB, padded stride 40
  __shared__ float QRs[2048];                    // Q [0,1024), R [1024,2048): [cs][k:2][32]
  __shared__ float partial[4][128];

  const int t = threadIdx.x;
  const int w = t >> 6;
  const int wm = w >> 2, wn = w & 3;
  const int ln = t & 15;
  const int lq = (t >> 4) & 3;
  const int k0 = blockIdx.x * 2;
  // gen role: mi = w (0..7); row = mi*16+ln
  const int grow = w * 16 + ln;
  const int gb = grow & 63;
  const int gkk = grow >> 6;

  // ---- QRs staging (once) ----
  if (t < 256) {
    int idx = t * 4, cs = idx >> 6, rem = idx & 63;
    *(f32x4*)(&QRs[idx]) = *(const f32x4*)(Qf + cs * 65536 + k0 * 32 + rem);
  } else {
    int idx = (t - 256) * 4, cs = idx >> 6, rem = idx & 63;
    *(f32x4*)(&QRs[1024 + idx]) = *(const f32x4*)(Rf + cs * 65536 + k0 * 32 + rem);
  }

  const float rb = rep[gb * 2048 + k0 + gkk];
  const float* pbase = Pf + gb * 32 + lq * 8;           // + cs*2048
  const unsigned short* bsrc = W2f + t * 16;            // + cs*8192
  const int bo = t >> 1;
  const int bi0 = (t & 1) * 16;

  f32x4 acc[4][4];
  #pragma unroll
  for (int mi = 0; mi < 4; ++mi)
    #pragma unroll
    for (int nj = 0; nj < 4; ++nj) acc[mi][nj] = (f32x4){0.f, 0.f, 0.f, 0.f};

  // gen chunk cs into Abuf[par] from reg P + LDS Q/R
  auto gen = [&](int cs, int par, f32x4 pa, f32x4 pb) {
    const float* q = &QRs[cs * 64 + gkk * 32 + lq * 8];
    f32x4 qa = *(const f32x4*)q;
    f32x4 qb = *(const f32x4*)(q + 4);
    f32x4 ra = *(const f32x4*)(q + 1024);
    f32x4 rc = *(const f32x4*)(q + 1028);
    unsigned u[8];
    #pragma unroll
    for (int j = 0; j < 4; ++j) {
      float z0 = fmaf(-rb, ra[j], pa[j] + qa[j]);
      float z1 = fmaf(-rb, rc[j], pb[j] + qb[j]);
      u[j]     = __float_as_uint(fmaxf(z0, 0.f)) + 0x8000u;
      u[j + 4] = __float_as_uint(fmaxf(z1, 0.f)) + 0x8000u;
    }
    unsigned d0 = __builtin_amdgcn_perm(u[1], u[0], 0x07060302);
    unsigned d1 = __builtin_amdgcn_perm(u[3], u[2], 0x07060302);
    unsigned d2 = __builtin_amdgcn_perm(u[5], u[4], 0x07060302);
    unsigned d3 = __builtin_amdgcn_perm(u[7], u[6], 0x07060302);
    *(uint4*)(&Abuf[par][t * 8]) = make_uint4(d0, d1, d2, d3);
  };

  // ---- prologue ----
  f32x4 PregA[2], PregB[2];
  uint4 Breg0[2], Breg1[2];
  // P(0), B(0) to temps
  PregA[0] = *(const f32x4*)(pbase);
  PregB[0] = *(const f32x4*)(pbase + 4);
  Breg0[0] = *(const uint4*)(bsrc);
  Breg1[0] = *(const uint4*)(bsrc + 8);
  __syncthreads();  // QRs visible
  gen(0, 0, PregA[0], PregB[0]);
  *(uint4*)(&Bbuf[0][bo * 40 + bi0])     = Breg0[0];
  *(uint4*)(&Bbuf[0][bo * 40 + bi0 + 8]) = Breg1[0];
  // P(1), B(1)
  PregA[1] = *(const f32x4*)(pbase + 2048);
  PregB[1] = *(const f32x4*)(pbase + 2048 + 4);
  Breg0[1] = *(const uint4*)(bsrc + 8192);
  Breg1[1] = *(const uint4*)(bsrc + 8192 + 8);
  __syncthreads();  // Abuf[0], Bbuf[0] visible

  // ---- K loop: invariants at top of iter cs:
  //   Abuf[cs&1]=A(cs), Bbuf[cs&1]=B(cs), Preg[(cs+1)&1]=P(cs+1), Breg[(cs+1)&1]=B(cs+1)
  #pragma unroll
  for (int cs = 0; cs < 16; ++cs) {
    const int par = cs & 1;
    // fragments for this chunk
    short8 afr[4], bfr[4];
    #pragma unroll
    for (int j = 0; j < 4; ++j)
      afr[j] = *(const short8*)(&Abuf[par][(((wm * 4 + j) * 4 + lq) * 16 + ln) * 8]);
    #pragma unroll
    for (int nj = 0; nj < 4; ++nj)
      bfr[nj] = *(const short8*)(&Bbuf[par][(wn * 64 + nj * 16 + ln) * 40 + lq * 8]);
    if (cs < 15) {
      // stage B(cs+1) regs -> LDS; gen A(cs+1)
      *(uint4*)(&Bbuf[par ^ 1][bo * 40 + bi0])     = Breg0[par ^ 1];
      *(uint4*)(&Bbuf[par ^ 1][bo * 40 + bi0 + 8]) = Breg1[par ^ 1];
      gen(cs + 1, par ^ 1, PregA[par ^ 1], PregB[par ^ 1]);
    }
    if (cs < 14) {
      // load P(cs+2), B(cs+2) into parity (cs&1)
      PregA[par] = *(const f32x4*)(pbase + (cs + 2) * 2048);
      PregB[par] = *(const f32x4*)(pbase + (cs + 2) * 2048 + 4);
      Breg0[par] = *(const uint4*)(bsrc + (cs + 2) * 8192);
      Breg1[par] = *(const uint4*)(bsrc + (cs + 2) * 8192 + 8);
    }
    #pragma unroll
    for (int j = 0; j < 4; ++j)
      #pragma unroll
      for (int nj = 0; nj < 4; ++nj)
        acc[j][nj] = __builtin_amdgcn_mfma_f32_16x16x32_bf16(afr[j], bfr[nj], acc[j][nj], 0, 0, 0);
    __syncthreads();
  }

  // ---- epilogue: u = relu(t2[o]*acc + c2[o]) * W3[o]; reduce over o ----
  float t2v[4], c2v[4], w3v[4];
  #pragma unroll
  for (int nj = 0; nj < 4; ++nj) {
    int o = wn * 64 + nj * 16 + ln;
    t2v[nj] = t2[o];
    c2v[nj] = c2[o];
    w3v[nj] = W3[o];
  }
  #pragma unroll
  for (int j = 0; j < 4; ++j) {
    float s[4] = {0.f, 0.f, 0.f, 0.f};
    #pragma unroll
    for (int nj = 0; nj < 4; ++nj)
      #pragma unroll
      for (int r = 0; r < 4; ++r) {
        float u = fmaf(t2v[nj], acc[j][nj][r], c2v[nj]);
        u = fmaxf(u, 0.f);
        s[r] = fmaf(u, w3v[nj], s[r]);
      }
    #pragma unroll
    for (int r = 0; r < 4; ++r) {
      #pragma unroll
      for (int m = 1; m < 16; m <<= 1) s[r] += __shfl_xor(s[r], m, 64);
    }
    if (ln == 0) {
      #pragma unroll
      for (int r = 0; r < 4; ++r)
        partial[wn][wm * 64 + j * 16 + lq * 4 + r] = s[r];
    }
  }
  __syncthreads();
  if (t < 128) {
    out[(t & 63) * 2048 + k0 + (t >> 6)] =
        partial[0][t] + partial[1][t] + partial[2][t] + partial[3][t] + b3[0];
  }
}

extern "C" void kernel_launch(void* const* d_in, const int* in_sizes, int n_in,
                              void* d_out, int out_size, void* d_ws, size_t ws_size,
                              hipStream_t stream) {
  const float* rep   = (const float*)d_in[0];
  const float* emb   = (const float*)d_in[1];
  const float* W1    = (const float*)d_in[2];
  const float* b1    = (const float*)d_in[3];
  const float* g1    = (const float*)d_in[4];
  const float* beta1 = (const float*)d_in[5];
  const float* m1    = (const float*)d_in[6];
  const float* v1    = (const float*)d_in[7];
  const float* W2    = (const float*)d_in[8];
  const float* b2    = (const float*)d_in[9];
  const float* g2    = (const float*)d_in[10];
  const float* beta2 = (const float*)d_in[11];
  const float* m2    = (const float*)d_in[12];
  const float* v2    = (const float*)d_in[13];
  const float* W3    = (const float*)d_in[14];
  const float* b3    = (const float*)d_in[15];
  float* out = (float*)d_out;

  char* ws = (char*)d_ws;
  float* t2           = (float*)(ws + 0);        // 256 f32
  float* c2           = (float*)(ws + 1024);     // 256 f32
  float* Pf           = (float*)(ws + 4096);     // 16x64x32 f32 = 128 KB
  float* Qf           = (float*)(ws + 262144);   // 16x2048x32 f32 = 4 MB
  float* Rf           = (float*)(ws + 4456448);  // 4 MB
  unsigned short* W2f = (unsigned short*)(ws + 8650752);  // 16x256x32 bf16 = 256 KB

  prep_all<<<385, 256, 0, stream>>>(rep, emb, W1, g1, v1, b1, m1, beta1,
                                    W2, g2, v2, b2, m2, beta2,
                                    Qf, Rf, W2f, t2, c2, Pf);
  fused_main<<<1024, 512, 0, stream>>>(rep, Pf, Qf, Rf, W2f, t2, c2, W3, b3, out);
}

// Round 7
// 194.526 us; speedup vs baseline: 1.1702x; 1.1702x over previous
//
#include <hip/hip_runtime.h>
#include <hip/hip_bf16.h>

#define EPS 1e-5f
// B=64, D=2048, E=64, H1=512, H2=256

typedef __attribute__((ext_vector_type(8))) short short8;
typedef __attribute__((ext_vector_type(4))) float f32x4;

__device__ __forceinline__ unsigned short f2bf(float f) {
  unsigned u = __float_as_uint(f);
  u = u + 0x7FFFu + ((u >> 16) & 1u);  // RNE
  return (unsigned short)(u >> 16);
}
__device__ __forceinline__ unsigned pack2(float a, float b) {
  return (unsigned)f2bf(a) | ((unsigned)f2bf(b) << 16);
}
__device__ __forceinline__ unsigned packbf2(float a, float b) {
  union { __hip_bfloat162 h; unsigned u; } cv;
  cv.h = __float22bfloat162_rn(make_float2(a, b));  // v_cvt_pk_bf16_f32 on gfx950
  return cv.u;
}

// ================= merged prep (385 blocks x 256 thr) =================
// x<256    : Qf/Rf (fp32, frag layout [cs:16][k:2048][32]) for 8 k each
// 256..319 : W2f (bf16, frag layout [cs:16][o:256][32])
// x==320   : t2, c2
// 321..384 : Pfb rows for b = x-321 (bf16 pairs, layout [cs:16][b:64][16 uint])
__global__ __launch_bounds__(256) void prep_all(
    const float* __restrict__ rep,
    const float* __restrict__ emb, const float* __restrict__ W1,
    const float* __restrict__ g1, const float* __restrict__ v1,
    const float* __restrict__ b1, const float* __restrict__ m1,
    const float* __restrict__ beta1,
    const float* __restrict__ W2,
    const float* __restrict__ g2, const float* __restrict__ v2,
    const float* __restrict__ b2, const float* __restrict__ m2,
    const float* __restrict__ beta2,
    float* __restrict__ Qf, float* __restrict__ Rf,
    unsigned short* __restrict__ W2f,
    float* __restrict__ t2, float* __restrict__ c2,
    unsigned* __restrict__ Pfb) {
  __shared__ float red[4 * 512];
  const int x = blockIdx.x, t = threadIdx.x;
  if (x < 256) {
    const int k0 = x * 8;
    const int h = t * 2;
    const float a0 = g1[h] * rsqrtf(v1[h] + EPS);
    const float a1 = g1[h + 1] * rsqrtf(v1[h + 1] + EPS);
    const float* We = W1 + 2048 * 512;
    float acc0[8], acc1[8];
    #pragma unroll
    for (int k = 0; k < 8; ++k) { acc0[k] = 0.f; acc1[k] = 0.f; }
    for (int e = 0; e < 64; ++e) {
      float2 wv = *(const float2*)(We + e * 512 + h);
      #pragma unroll
      for (int k = 0; k < 8; ++k) {
        float ev = emb[(k0 + k) * 64 + e];  // block-uniform
        acc0[k] = fmaf(ev, wv.x, acc0[k]);
        acc1[k] = fmaf(ev, wv.y, acc1[k]);
      }
    }
    const int cs = h >> 5;
    const int rm = h & 31;
    #pragma unroll
    for (int k = 0; k < 8; ++k) {
      const int kk = k0 + k;
      *(float2*)(Qf + cs * 65536 + kk * 32 + rm) = make_float2(a0 * acc0[k], a1 * acc1[k]);
      float2 wv = *(const float2*)(W1 + (size_t)kk * 512 + h);
      *(float2*)(Rf + cs * 65536 + kk * 32 + rm) = make_float2(a0 * wv.x, a1 * wv.y);
    }
  } else if (x < 320) {
    const int h0 = (x - 256) * 8;
    const int o = t;
    unsigned d[4];
    #pragma unroll
    for (int i = 0; i < 4; ++i) {
      float v0 = W2[(h0 + 2 * i) * 256 + o];
      float v1_ = W2[(h0 + 2 * i + 1) * 256 + o];
      d[i] = pack2(v0, v1_);
    }
    const int cs = h0 >> 5;
    const int rm = h0 & 31;
    *(uint4*)(W2f + cs * 8192 + o * 32 + rm) = make_uint4(d[0], d[1], d[2], d[3]);
  } else if (x == 320) {
    float tv = g2[t] * rsqrtf(v2[t] + EPS);
    t2[t] = tv;
    c2[t] = tv * (b2[t] - m2[t]) + beta2[t];
  } else {
    // Pfb for b = x - 321
    const int b = x - 321;
    const int lane = t & 63, kq = t >> 6;
    const int h = lane * 8;
    const float* wp = W1 + (size_t)(kq * 512) * 512 + h;
    const float* rp = rep + b * 2048 + kq * 512;
    float acc[8];
    #pragma unroll
    for (int i = 0; i < 8; ++i) acc[i] = 0.f;
    #pragma unroll 4
    for (int k = 0; k < 512; ++k) {
      f32x4 wa = *(const f32x4*)(wp + (size_t)k * 512);
      f32x4 wb = *(const f32x4*)(wp + (size_t)k * 512 + 4);
      float rk = rp[k];  // wave-uniform
      acc[0] = fmaf(rk, wa[0], acc[0]); acc[1] = fmaf(rk, wa[1], acc[1]);
      acc[2] = fmaf(rk, wa[2], acc[2]); acc[3] = fmaf(rk, wa[3], acc[3]);
      acc[4] = fmaf(rk, wb[0], acc[4]); acc[5] = fmaf(rk, wb[1], acc[5]);
      acc[6] = fmaf(rk, wb[2], acc[6]); acc[7] = fmaf(rk, wb[3], acc[7]);
    }
    *(f32x4*)(&red[kq * 512 + h])     = (f32x4){acc[0], acc[1], acc[2], acc[3]};
    *(f32x4*)(&red[kq * 512 + h + 4]) = (f32x4){acc[4], acc[5], acc[6], acc[7]};
    __syncthreads();
    // thread t handles h-pair (2t, 2t+1)
    {
      const int h0 = 2 * t, h1 = 2 * t + 1;
      float tot0 = red[h0] + red[512 + h0] + red[1024 + h0] + red[1536 + h0];
      float tot1 = red[h1] + red[512 + h1] + red[1024 + h1] + red[1536 + h1];
      float a0 = g1[h0] * rsqrtf(v1[h0] + EPS);
      float a1 = g1[h1] * rsqrtf(v1[h1] + EPS);
      float val0 = fmaf(a0, tot0, fmaf(a0, b1[h0] - m1[h0], beta1[h0]));
      float val1 = fmaf(a1, tot1, fmaf(a1, b1[h1] - m1[h1], beta1[h1]));
      // cs = t>>4, pair index = t&15
      Pfb[(t >> 4) * 1024 + b * 16 + (t & 15)] = pack2(val0, val1);
    }
  }
}

// ================= fused main =================
// 2048 blocks x 256 thr (4 waves), block tile M=64 (1 k) x N=256, K=512.
// K processed in 4 barrier intervals of 128 (4 chunks of 32): 256 MFMA per
// block-interval. A gen'd into LDS frag-order (1x redundancy, thread t owns
// frag (mi=w, lq, ln) per chunk): ds_write linear b128, afr reads 1KB
// contiguous -> conflict-free. Gen sources: P from bf16 Pfb (coalesced 16B),
// Q/R from global (4-address broadcast, L2-hot). B-frags direct from W2f
// (1KB contiguous). No barrier inside an interval -> compiler software-
// pipelines the 4-chunk straight-line body.
__global__ __launch_bounds__(256, 3) void fused_main(
    const float* __restrict__ rep,
    const unsigned* __restrict__ Pfb,
    const float* __restrict__ Qf,
    const float* __restrict__ Rf,
    const unsigned short* __restrict__ W2f,
    const float* __restrict__ t2, const float* __restrict__ c2,
    const float* __restrict__ W3, const float* __restrict__ b3,
    float* __restrict__ out) {
  __shared__ unsigned short Abuf[2][8192];  // 2 x 16KB: [chunk:4][frag-order 2048]
  __shared__ float partial[4][64];

  const int t = threadIdx.x;
  const int w = t >> 6;
  const int ln = t & 15;
  const int lq = (t >> 4) & 3;
  const int k0 = blockIdx.x;
  const int gb = w * 16 + ln;  // row this thread gens (b index)

  const float rb = rep[gb * 2048 + k0];
  const unsigned* pbase = Pfb + gb * 16 + lq * 4;       // + cs*1024
  const float* qbase = Qf + k0 * 32 + lq * 8;           // + cs*65536
  const float* rbase = Rf + k0 * 32 + lq * 8;           // + cs*65536
  const unsigned short* wbase = W2f + (w * 64 + ln) * 32 + lq * 8;  // + cs*8192 + nj*512

  f32x4 acc[4][4];
  #pragma unroll
  for (int mi = 0; mi < 4; ++mi)
    #pragma unroll
    for (int nj = 0; nj < 4; ++nj) acc[mi][nj] = (f32x4){0.f, 0.f, 0.f, 0.f};

  // generate one 8-wide A-frag for chunk cs into Abuf[par] slot ci
  auto gen1 = [&](int cs, int ci, int par) {
    uint4 pv = *(const uint4*)(pbase + cs * 1024);
    f32x4 qa = *(const f32x4*)(qbase + cs * 65536);
    f32x4 qb = *(const f32x4*)(qbase + cs * 65536 + 4);
    f32x4 ra = *(const f32x4*)(rbase + cs * 65536);
    f32x4 rc = *(const f32x4*)(rbase + cs * 65536 + 4);
    float q8[8] = {qa[0], qa[1], qa[2], qa[3], qb[0], qb[1], qb[2], qb[3]};
    float r8[8] = {ra[0], ra[1], ra[2], ra[3], rc[0], rc[1], rc[2], rc[3]};
    unsigned pw[4] = {pv.x, pv.y, pv.z, pv.w};
    unsigned d[4];
    #pragma unroll
    for (int i = 0; i < 4; ++i) {
      float p0 = __uint_as_float(pw[i] << 16);
      float p1 = __uint_as_float(pw[i] & 0xffff0000u);
      float z0 = fmaf(-rb, r8[2 * i],     p0 + q8[2 * i]);
      float z1 = fmaf(-rb, r8[2 * i + 1], p1 + q8[2 * i + 1]);
      d[i] = packbf2(fmaxf(z0, 0.f), fmaxf(z1, 0.f));
    }
    *(uint4*)(&Abuf[par][ci * 2048 + t * 8]) = make_uint4(d[0], d[1], d[2], d[3]);
  };

  // prologue: interval 0 (cs 0..3) into Abuf[0]
  #pragma unroll
  for (int ci = 0; ci < 4; ++ci) gen1(ci, ci, 0);

  #pragma unroll
  for (int iv = 0; iv < 4; ++iv) {
    const int par = iv & 1;
    __syncthreads();  // Abuf[par] ready; prior reads of Abuf[par^1] done
    #pragma unroll
    for (int ci = 0; ci < 4; ++ci) {
      const int cs = iv * 4 + ci;
      short8 afr[4], bfr[4];
      #pragma unroll
      for (int mi = 0; mi < 4; ++mi)
        afr[mi] = *(const short8*)(&Abuf[par][ci * 2048 + ((mi * 4 + lq) * 16 + ln) * 8]);
      #pragma unroll
      for (int nj = 0; nj < 4; ++nj)
        bfr[nj] = *(const short8*)(wbase + cs * 8192 + nj * 512);
      if (iv < 3) gen1(cs + 4, ci, par ^ 1);  // overlaps MFMA below (no barrier in interval)
      #pragma unroll
      for (int mi = 0; mi < 4; ++mi)
        #pragma unroll
        for (int nj = 0; nj < 4; ++nj)
          acc[mi][nj] = __builtin_amdgcn_mfma_f32_16x16x32_bf16(afr[mi], bfr[nj], acc[mi][nj], 0, 0, 0);
    }
  }

  // epilogue: u = relu(t2[o]*acc + c2[o]) * W3[o]; reduce over o
  float t2v[4], c2v[4], w3v[4];
  #pragma unroll
  for (int nj = 0; nj < 4; ++nj) {
    int o = w * 64 + nj * 16 + ln;
    t2v[nj] = t2[o];
    c2v[nj] = c2[o];
    w3v[nj] = W3[o];
  }
  #pragma unroll
  for (int mi = 0; mi < 4; ++mi) {
    float s[4] = {0.f, 0.f, 0.f, 0.f};
    #pragma unroll
    for (int nj = 0; nj < 4; ++nj)
      #pragma unroll
      for (int r = 0; r < 4; ++r) {
        float u = fmaf(t2v[nj], acc[mi][nj][r], c2v[nj]);
        u = fmaxf(u, 0.f);
        s[r] = fmaf(u, w3v[nj], s[r]);
      }
    #pragma unroll
    for (int r = 0; r < 4; ++r) {
      #pragma unroll
      for (int m = 1; m < 16; m <<= 1) s[r] += __shfl_xor(s[r], m, 64);
    }
    if (ln == 0) {
      #pragma unroll
      for (int r = 0; r < 4; ++r) partial[w][mi * 16 + lq * 4 + r] = s[r];
    }
  }
  __syncthreads();
  if (t < 64) {
    out[t * 2048 + k0] =
        partial[0][t] + partial[1][t] + partial[2][t] + partial[3][t] + b3[0];
  }
}

extern "C" void kernel_launch(void* const* d_in, const int* in_sizes, int n_in,
                              void* d_out, int out_size, void* d_ws, size_t ws_size,
                              hipStream_t stream) {
  const float* rep   = (const float*)d_in[0];
  const float* emb   = (const float*)d_in[1];
  const float* W1    = (const float*)d_in[2];
  const float* b1    = (const float*)d_in[3];
  const float* g1    = (const float*)d_in[4];
  const float* beta1 = (const float*)d_in[5];
  const float* m1    = (const float*)d_in[6];
  const float* v1    = (const float*)d_in[7];
  const float* W2    = (const float*)d_in[8];
  const float* b2    = (const float*)d_in[9];
  const float* g2    = (const float*)d_in[10];
  const float* beta2 = (const float*)d_in[11];
  const float* m2    = (const float*)d_in[12];
  const float* v2    = (const float*)d_in[13];
  const float* W3    = (const float*)d_in[14];
  const float* b3    = (const float*)d_in[15];
  float* out = (float*)d_out;

  char* ws = (char*)d_ws;
  float* t2           = (float*)(ws + 0);        // 256 f32
  float* c2           = (float*)(ws + 1024);     // 256 f32
  unsigned* Pfb       = (unsigned*)(ws + 4096);  // 16x64x16 uint (bf16 pairs) = 64 KB
  float* Qf           = (float*)(ws + 262144);   // 16x2048x32 f32 = 4 MB
  float* Rf           = (float*)(ws + 4456448);  // 4 MB
  unsigned short* W2f = (unsigned short*)(ws + 8650752);  // 16x256x32 bf16 = 256 KB

  prep_all<<<385, 256, 0, stream>>>(rep, emb, W1, g1, v1, b1, m1, beta1,
                                    W2, g2, v2, b2, m2, beta2,
                                    Qf, Rf, W2f, t2, c2, Pfb);
  fused_main<<<2048, 256, 0, stream>>>(rep, Pfb, Qf, Rf, W2f, t2, c2, W3, b3, out);
}